// Round 11
// baseline (244.034 us; speedup 1.0000x reference)
//
#include <hip/hip_runtime.h>
#include <hip/hip_bf16.h>

// GraphSAGE 2-layer forward. N=100000, E=1250000, 64 -> 64 -> 32, fp32.
//
// Round-11: dense2 fused into agg64 as an MFMA epilogue (block = 16 nodes,
// wave aggregates 4 nodes -> h1 in a 16x64 LDS tile -> each wave one 16x16
// MFMA tile). Round-9's fusion died on wcol[64] register spill; MFMA needs no
// per-lane W array. Kills the dense2 dispatch + the 51 MB h1 round-trip.
// P1_CHUNK 2048 (611 blocks; 8192 gave only 153 = 0.6 blocks/CU, starved).
//   zero     : gcursor = 0
//   p1       : bucket edges by dst>>8, pack (src<<8)|rel
//   p2       : per-bucket base (inline prefix) + LDS count/scan -> row_start+csr
//   dense1   : bufA(xs) = x@Ws1+b1 (f32), t1n = bf16(x@Wn1)  (MFMA split-bf16)
//   agg64_d2 : h1 = relu(xs + mean t1n[src]) (LDS tile);
//              d_out = h1@Ws2+b2, t2n = bf16(h1@Wn2)  (MFMA split-bf16)
//   agg32    : d_out += mean t2n[src]   (in place)

#define NF 64
#define BW 256            // bucket width (nodes); rel = dst & 255
#define BSH 8
#define MAXB 512          // max buckets (LDS arrays)
#define CAPMAX 8192       // max edges per bucket region (mean 3197)
#define P1_CHUNK 2048

typedef __attribute__((ext_vector_type(8))) short short8;
typedef __attribute__((ext_vector_type(8))) unsigned short ushort8v;
typedef __attribute__((ext_vector_type(4))) float floatx4;

__device__ __forceinline__ short bf16hi(float v) {
    __hip_bfloat16 h = __float2bfloat16(v);
    return *(short*)&h;
}
__device__ __forceinline__ float bf2f(short s) {
    __hip_bfloat16 h = *(__hip_bfloat16*)&s;
    return __bfloat162float(h);
}
__device__ __forceinline__ float bits2f(unsigned short u) {
    unsigned int x = ((unsigned int)u) << 16;
    union { unsigned int i; float f; } c; c.i = x; return c.f;
}

// ---------------- zero ----------------

__global__ __launch_bounds__(512) void zero_kernel(int* __restrict__ g) {
    if (threadIdx.x < MAXB) g[threadIdx.x] = 0;
}

// ---------------- CSR build: counting sort ----------------

__global__ __launch_bounds__(256) void p1_bucket_kernel(const int* __restrict__ src,
                                                        const int* __restrict__ dst,
                                                        int* __restrict__ gcursor,
                                                        unsigned* __restrict__ bucket,
                                                        int E, int nbuckets) {
    __shared__ int cnt[MAXB];
    __shared__ int cbase[MAXB];
    const int beg = blockIdx.x * P1_CHUNK;
    const int end = min(E, beg + P1_CHUNK);
    for (int i = threadIdx.x; i < nbuckets; i += 256) cnt[i] = 0;
    __syncthreads();
    for (int e = beg + threadIdx.x; e < end; e += 256)
        atomicAdd(&cnt[dst[e] >> BSH], 1);
    __syncthreads();
    for (int i = threadIdx.x; i < nbuckets; i += 256) {
        int c = cnt[i];
        cbase[i] = c ? atomicAdd(&gcursor[i], c) : 0;
        cnt[i] = 0;                              // reuse as local cursor
    }
    __syncthreads();
    for (int e = beg + threadIdx.x; e < end; e += 256) {
        int d = dst[e];
        int r = d >> BSH;
        int p = cbase[r] + atomicAdd(&cnt[r], 1);
        if (p < CAPMAX)                          // clamp: no OOB even if skewed
            bucket[(size_t)r * CAPMAX + p] = ((unsigned)src[e] << BSH) | (unsigned)(d & (BW - 1));
    }
}

// p2: one block per 256-node bucket; exclusive row_start segment + csr window.
__global__ __launch_bounds__(256) void p2_csr_kernel(const unsigned* __restrict__ bucket,
                                                     const int* __restrict__ gcursor,
                                                     int* __restrict__ row_start,
                                                     int* __restrict__ csr_src,
                                                     int N, int nbuckets) {
    __shared__ unsigned stage[CAPMAX];   // 32 KB
    __shared__ int cnt[BW];
    __shared__ int excl[BW];
    const int r = blockIdx.x;
    const int tid = threadIdx.x;

    // base = sum_{i<r} min(gcursor[i], CAPMAX)   (excl[] as scratch)
    int partial = 0;
    for (int i = tid; i < r; i += 256) partial += min(gcursor[i], CAPMAX);
    excl[tid] = partial;
    __syncthreads();
    for (int off = 128; off > 0; off >>= 1) {
        if (tid < off) excl[tid] += excl[tid + off];
        __syncthreads();
    }
    const int base = excl[0];
    const int sz = min(gcursor[r], CAPMAX);
    const unsigned* bsrc = bucket + (size_t)r * CAPMAX;
    __syncthreads();

    cnt[tid] = 0;
    __syncthreads();
    for (int i = tid; i < sz; i += 256) {
        unsigned v = bsrc[i];
        stage[i] = v;
        atomicAdd(&cnt[v & (BW - 1)], 1);
    }
    __syncthreads();
    // inclusive scan (Hillis-Steele, 1 elem/thread since BW == blockDim)
    excl[tid] = cnt[tid];
    __syncthreads();
    for (int off = 1; off < BW; off <<= 1) {
        int v0 = (tid >= off) ? excl[tid - off] : 0;
        __syncthreads();
        excl[tid] += v0;
        __syncthreads();
    }
    int node = r * BW + tid;
    if (node < N) row_start[node] = base + excl[tid] - cnt[tid];
    if (r == nbuckets - 1 && tid == 0) row_start[N] = base + sz;
    __syncthreads();
    cnt[tid] = excl[tid] - cnt[tid];             // exclusive cursors
    __syncthreads();
    for (int i = tid; i < sz; i += 256) {
        unsigned v = stage[i];
        int p = atomicAdd(&cnt[v & (BW - 1)], 1);
        csr_src[base + p] = (int)(v >> BSH);     // window owned by this block only
    }
}

// ---------------- MFMA dense1: [N][64] @ [64][128] ----------
// A layout: A[m=lane&15][k=(lane>>4)*8+j]; C/D: col=lane&15, row=(lane>>4)*4+reg.
// Weights split+transposed to bf16 hi/lo in LDS. t<4 -> f32 xs+bias; t>=4 -> bf16 t1n.

__global__ __launch_bounds__(256) void dense1_mfma_kernel(
        const float* __restrict__ X,                 // [N][64]
        const float* __restrict__ Wself,             // [64][64] k-major
        const float* __restrict__ Wneigh,            // [64][64] k-major
        const float* __restrict__ bias,              // [64]
        float* __restrict__ outA,                    // [N][64] f32
        unsigned short* __restrict__ outB,           // [N][64] bf16 bits
        int N) {
    constexpr int NT = 8, NSELF = 4, NO = 128, HALF = 64;
    __shared__ unsigned short wh[NO * 72];
    __shared__ unsigned short wl[NO * 72];
    const int tid = threadIdx.x;
    for (int i = tid; i < NO * 64; i += 256) {
        int n = i & (NO - 1), k = i / NO;            // consecutive tid -> coalesced
        float v = (n < HALF) ? Wself[k * HALF + n] : Wneigh[k * HALF + (n - HALF)];
        short hv = bf16hi(v);
        wh[n * 72 + k] = (unsigned short)hv;
        wl[n * 72 + k] = (unsigned short)bf16hi(v - bf2f(hv));
    }

    const int lane = tid & 63;
    const int wid  = tid >> 6;
    const int m = lane & 15, quad = lane >> 4;
    const int rowblk = blockIdx.x * 128 + wid * 32;

    floatx4 acc[2][NT];
    #pragma unroll
    for (int rt = 0; rt < 2; ++rt)
        #pragma unroll
        for (int t = 0; t < NT; ++t) acc[rt][t] = (floatx4)(0.f);

    short8 ah[2][2], al[2][2];   // [rowset][k-half]
    #pragma unroll
    for (int rt = 0; rt < 2; ++rt) {
        int r = rowblk + rt * 16 + m;
        if (r >= N) r = N - 1;                       // clamped load, store guarded
        const float* xp = X + (size_t)r * 64 + quad * 8;
        #pragma unroll
        for (int h = 0; h < 2; ++h) {
            floatx4 f0 = *(const floatx4*)(xp + h * 32);
            floatx4 f1 = *(const floatx4*)(xp + h * 32 + 4);
            short8 hi, lo;
            #pragma unroll
            for (int j = 0; j < 4; ++j) {
                short hv = bf16hi(f0[j]);
                hi[j] = hv; lo[j] = bf16hi(f0[j] - bf2f(hv));
                short hv2 = bf16hi(f1[j]);
                hi[4 + j] = hv2; lo[4 + j] = bf16hi(f1[j] - bf2f(hv2));
            }
            ah[rt][h] = hi; al[rt][h] = lo;
        }
    }
    __syncthreads();                                 // weights staged

    #pragma unroll
    for (int t = 0; t < NT; ++t) {
        int n = t * 16 + m;
        const unsigned short* ph = wh + n * 72 + quad * 8;
        const unsigned short* pl = wl + n * 72 + quad * 8;
        #pragma unroll
        for (int h = 0; h < 2; ++h) {
            short8 bh = *(const short8*)(ph + h * 32);
            short8 bl = *(const short8*)(pl + h * 32);
            #pragma unroll
            for (int rt = 0; rt < 2; ++rt) {
                acc[rt][t] = __builtin_amdgcn_mfma_f32_16x16x32_bf16(ah[rt][h], bh, acc[rt][t], 0, 0, 0);
                acc[rt][t] = __builtin_amdgcn_mfma_f32_16x16x32_bf16(al[rt][h], bh, acc[rt][t], 0, 0, 0);
                acc[rt][t] = __builtin_amdgcn_mfma_f32_16x16x32_bf16(ah[rt][h], bl, acc[rt][t], 0, 0, 0);
            }
        }
    }

    #pragma unroll
    for (int rt = 0; rt < 2; ++rt) {
        #pragma unroll
        for (int t = 0; t < NT; ++t) {
            #pragma unroll
            for (int r4 = 0; r4 < 4; ++r4) {
                int row = rowblk + rt * 16 + quad * 4 + r4;
                if (row < N) {
                    if (t < NSELF) {
                        int col = t * 16 + m;
                        outA[(size_t)row * 64 + col] = acc[rt][t][r4] + bias[col];
                    } else {
                        int col = (t - NSELF) * 16 + m;
                        outB[(size_t)row * 64 + col] = (unsigned short)bf16hi(acc[rt][t][r4]);
                    }
                }
            }
        }
    }
}

// ---------------- fused agg64 + dense2 (MFMA epilogue) ----------------
// Block = 16 nodes. Each wave aggregates 4 nodes (proven ILP-2 gather +
// butterfly), h1 rows to a 16x64 LDS tile; then each wave computes one 16x16
// output tile via split-bf16 MFMA. cols 0-31 -> d_out(+b2) f32, 32-63 -> t2n.

__global__ __launch_bounds__(256) void agg64_d2_kernel(
        const unsigned short* __restrict__ t1n,      // [N][64] bf16 bits
        const float* __restrict__ xs,                // [N][64] self+bias
        const int* __restrict__ row_start,
        const int* __restrict__ csr_src,
        const float* __restrict__ Ws2,               // [64][32] k-major
        const float* __restrict__ Wn2,               // [64][32] k-major
        const float* __restrict__ b2,                // [32]
        float* __restrict__ outD,                    // [N][32] (d_out)
        unsigned short* __restrict__ t2n,            // [N][32] bf16 bits
        int N) {
    __shared__ unsigned short w2h[64 * 72];          // 9 KB
    __shared__ unsigned short w2l[64 * 72];          // 9 KB
    __shared__ float h1s[16][64];                    // 4 KB
    const int tid = threadIdx.x;
    for (int i = tid; i < 64 * 64; i += 256) {
        int n = i & 63, k = i >> 6;
        float v = (n < 32) ? Ws2[k * 32 + n] : Wn2[k * 32 + (n - 32)];
        short hv = bf16hi(v);
        w2h[n * 72 + k] = (unsigned short)hv;
        w2l[n * 72 + k] = (unsigned short)bf16hi(v - bf2f(hv));
    }

    const int lane = tid & 63;
    const int wid  = tid >> 6;
    const int g = lane >> 3, c = lane & 7;           // 8 groups x 8 lanes
    const int nbase = blockIdx.x * 16;

    for (int q = 0; q < 4; ++q) {                    // 4 nodes per wave
        const int ln = wid * 4 + q;
        const int n = nbase + ln;
        float acc[8] = {0.f, 0.f, 0.f, 0.f, 0.f, 0.f, 0.f, 0.f};
        int beg = 0, end = 0;
        if (n < N) { beg = row_start[n]; end = row_start[n + 1]; }
        for (int j = beg + g; j < end; j += 16) {
            int j2 = j + 8;
            int s0 = csr_src[j];
            ushort8v u0 = *(const ushort8v*)(t1n + (size_t)s0 * 64 + c * 8);
            if (j2 < end) {
                int s1 = csr_src[j2];
                ushort8v u1 = *(const ushort8v*)(t1n + (size_t)s1 * 64 + c * 8);
                #pragma unroll
                for (int i = 0; i < 8; ++i) acc[i] += bits2f(u0[i]) + bits2f(u1[i]);
            } else {
                #pragma unroll
                for (int i = 0; i < 8; ++i) acc[i] += bits2f(u0[i]);
            }
        }
        #pragma unroll
        for (int i = 0; i < 8; ++i) {
            float v = acc[i];
            v += __shfl_xor(v, 8);
            v += __shfl_xor(v, 16);
            v += __shfl_xor(v, 32);
            acc[i] = v;
        }
        if (g == 0) {
            if (n < N) {
                float invd = 1.0f / fmaxf((float)(end - beg), 1.0f);
                size_t o = (size_t)n * 64 + c * 8;
                floatx4 x0 = *(const floatx4*)(xs + o);
                floatx4 x1 = *(const floatx4*)(xs + o + 4);
                floatx4 h0, h1v;
                #pragma unroll
                for (int i = 0; i < 4; ++i) {
                    h0[i]  = fmaxf(x0[i] + acc[i] * invd, 0.f);
                    h1v[i] = fmaxf(x1[i] + acc[4 + i] * invd, 0.f);
                }
                *(floatx4*)&h1s[ln][c * 8]     = h0;
                *(floatx4*)&h1s[ln][c * 8 + 4] = h1v;
            } else {
                *(floatx4*)&h1s[ln][c * 8]     = (floatx4)(0.f);
                *(floatx4*)&h1s[ln][c * 8 + 4] = (floatx4)(0.f);
            }
        }
    }
    __syncthreads();                                 // h1 tile + weights ready

    // dense2: wave wid -> output cols wid*16 .. wid*16+15
    const int m = lane & 15, quad = lane >> 4;
    short8 ah[2], al[2];                             // A = h1s, split hi/lo
    #pragma unroll
    for (int h = 0; h < 2; ++h) {
        const float* hp = &h1s[m][quad * 8 + h * 32];
        floatx4 f0 = *(const floatx4*)hp;
        floatx4 f1 = *(const floatx4*)(hp + 4);
        short8 hi, lo;
        #pragma unroll
        for (int j = 0; j < 4; ++j) {
            short hv = bf16hi(f0[j]);
            hi[j] = hv; lo[j] = bf16hi(f0[j] - bf2f(hv));
            short hv2 = bf16hi(f1[j]);
            hi[4 + j] = hv2; lo[4 + j] = bf16hi(f1[j] - bf2f(hv2));
        }
        ah[h] = hi; al[h] = lo;
    }
    floatx4 acc2 = (floatx4)(0.f);
    const int coln = wid * 16 + m;
    const unsigned short* ph = w2h + coln * 72 + quad * 8;
    const unsigned short* pl = w2l + coln * 72 + quad * 8;
    #pragma unroll
    for (int h = 0; h < 2; ++h) {
        short8 bh = *(const short8*)(ph + h * 32);
        short8 bl = *(const short8*)(pl + h * 32);
        acc2 = __builtin_amdgcn_mfma_f32_16x16x32_bf16(ah[h], bh, acc2, 0, 0, 0);
        acc2 = __builtin_amdgcn_mfma_f32_16x16x32_bf16(al[h], bh, acc2, 0, 0, 0);
        acc2 = __builtin_amdgcn_mfma_f32_16x16x32_bf16(ah[h], bl, acc2, 0, 0, 0);
    }
    #pragma unroll
    for (int r4 = 0; r4 < 4; ++r4) {
        int node = nbase + quad * 4 + r4;
        if (node < N) {
            if (coln < 32) outD[(size_t)node * 32 + coln] = acc2[r4] + b2[coln];
            else t2n[(size_t)node * 32 + (coln - 32)] = (unsigned short)bf16hi(acc2[r4]);
        }
    }
}

// ---------------- agg32: d_out += mean t2n[src], in place ----------------

__global__ __launch_bounds__(256) void agg32_kernel(float* io,  // [N][32] (d_out)
                                                    const unsigned short* __restrict__ t2n,
                                                    const int* __restrict__ row_start,
                                                    const int* __restrict__ csr_src, int N) {
    int n = (blockIdx.x * blockDim.x + threadIdx.x) >> 6;
    if (n >= N) return;
    int lane = threadIdx.x & 63;
    int g = lane >> 2, c = lane & 3;                 // lane covers feats c*8..c*8+7
    int beg = row_start[n], end = row_start[n + 1];
    float acc[8] = {0.f, 0.f, 0.f, 0.f, 0.f, 0.f, 0.f, 0.f};
    for (int j = beg + g; j < end; j += 32) {
        int j2 = j + 16;
        int s0 = csr_src[j];
        ushort8v u0 = *(const ushort8v*)(t2n + (size_t)s0 * 32 + c * 8);
        if (j2 < end) {
            int s1 = csr_src[j2];
            ushort8v u1 = *(const ushort8v*)(t2n + (size_t)s1 * 32 + c * 8);
            #pragma unroll
            for (int i = 0; i < 8; ++i) acc[i] += bits2f(u0[i]) + bits2f(u1[i]);
        } else {
            #pragma unroll
            for (int i = 0; i < 8; ++i) acc[i] += bits2f(u0[i]);
        }
    }
    #pragma unroll
    for (int i = 0; i < 8; ++i) {
        float v = acc[i];
        v += __shfl_xor(v, 4);
        v += __shfl_xor(v, 8);
        v += __shfl_xor(v, 16);
        v += __shfl_xor(v, 32);
        acc[i] = v;
    }
    if (g == 0) {
        float inv = 1.0f / fmaxf((float)(end - beg), 1.0f);
        size_t o = (size_t)n * 32 + c * 8;
        floatx4 s0 = *(const floatx4*)(io + o);
        floatx4 s1 = *(const floatx4*)(io + o + 4);
        floatx4 r0, r1;
        #pragma unroll
        for (int i = 0; i < 4; ++i) {
            r0[i] = s0[i] + acc[i] * inv;
            r1[i] = s1[i] + acc[4 + i] * inv;
        }
        *(floatx4*)(io + o) = r0;
        *(floatx4*)(io + o + 4) = r1;
    }
}

// ---------------- fallback (round-2 atomic path) ----------------

__global__ __launch_bounds__(256) void deg_kernel(const int* __restrict__ dst,
                                                  float* __restrict__ deg, int E) {
    int e = blockIdx.x * blockDim.x + threadIdx.x;
    if (e < E) atomicAdd(&deg[dst[e]], 1.0f);
}

__global__ __launch_bounds__(256) void agg_atomic_kernel(const float* __restrict__ feats,
                                                         const int* __restrict__ src,
                                                         const int* __restrict__ dst,
                                                         float* __restrict__ agg, int E) {
    int tid = blockIdx.x * blockDim.x + threadIdx.x;
    if (tid >= E * NF) return;
    int e = tid >> 6, f = tid & 63;
    atomicAdd(&agg[(size_t)dst[e] * NF + f], feats[(size_t)src[e] * NF + f]);
}

__global__ __launch_bounds__(256) void layer1_fb_kernel(const float* __restrict__ x,
                                                        const float* __restrict__ agg,
                                                        const float* __restrict__ deg,
                                                        const float* __restrict__ Wself,
                                                        const float* __restrict__ Wneigh,
                                                        const float* __restrict__ b,
                                                        float* __restrict__ h1, int N) {
    int tid = blockIdx.x * blockDim.x + threadIdx.x;
    if (tid >= N * NF) return;
    int n = tid >> 6, c = tid & 63;
    float inv = 1.0f / fmaxf(deg[n], 1.0f);
    const float* xrow = x + (size_t)n * NF;
    const float* arow = agg + (size_t)n * NF;
    float acc = b[c];
    #pragma unroll
    for (int k = 0; k < NF; ++k) {
        acc += xrow[k] * Wself[k * NF + c];
        acc += (arow[k] * inv) * Wneigh[k * NF + c];
    }
    h1[tid] = fmaxf(acc, 0.f);
}

__global__ __launch_bounds__(256) void layer2_fb_kernel(const float* __restrict__ h1,
                                                        const float* __restrict__ agg,
                                                        const float* __restrict__ deg,
                                                        const float* __restrict__ Wself,
                                                        const float* __restrict__ Wneigh,
                                                        const float* __restrict__ b,
                                                        float* __restrict__ out, int N) {
    int tid = blockIdx.x * blockDim.x + threadIdx.x;
    if (tid >= N * 32) return;
    int n = tid >> 5, c = tid & 31;
    float inv = 1.0f / fmaxf(deg[n], 1.0f);
    const float* hrow = h1 + (size_t)n * NF;
    const float* arow = agg + (size_t)n * NF;
    float acc = b[c];
    #pragma unroll
    for (int k = 0; k < NF; ++k) {
        acc += hrow[k] * Wself[k * 32 + c];
        acc += (arow[k] * inv) * Wneigh[k * 32 + c];
    }
    out[tid] = acc;
}

// ---------------- launch ----------------

extern "C" void kernel_launch(void* const* d_in, const int* in_sizes, int n_in,
                              void* d_out, int out_size, void* d_ws, size_t ws_size,
                              hipStream_t stream) {
    const float* x        = (const float*)d_in[0];
    const int*   src      = (const int*)d_in[1];
    const int*   dst      = (const int*)d_in[2];
    const float* W_self1  = (const float*)d_in[3];
    const float* W_neigh1 = (const float*)d_in[4];
    const float* b1       = (const float*)d_in[5];
    const float* W_self2  = (const float*)d_in[6];
    const float* W_neigh2 = (const float*)d_in[7];
    const float* b2       = (const float*)d_in[8];
    float* out = (float*)d_out;

    const int N = in_sizes[0] / NF;          // 100000
    const int E = in_sizes[1];               // 1250000
    const int nbuckets = (N + BW - 1) / BW;  // 391

    // ws layout; gather tables 128B-aligned (round-10 proven: unaligned t1n
    // rows straddle 2 cachelines -> +70% FETCH)
    const size_t rsPad = ((size_t)N + 8) & ~7ull;
    int* gcursor   = (int*)d_ws;                      // [MAXB]
    int* row_start = gcursor + MAXB;                  // [N+1] padded
    int* csr_src   = row_start + rsPad;               // [E]
    uintptr_t pa = (uintptr_t)(csr_src + (((size_t)E + 7) & ~7ull));
    pa = (pa + 127) & ~(uintptr_t)127;                // 128B align
    float* bufA = (float*)pa;                         // [N][64] f32 (xs)
    unsigned* bucket = (unsigned*)bufA;               // [nbuckets][CAPMAX], dead before dense1
    unsigned short* t1n = (unsigned short*)(bufA + (size_t)N * NF);  // [N][64] bf16, 128B rows
    unsigned short* t2n = t1n + (size_t)N * NF;                      // [N][32] bf16, 64B rows
    size_t need = (size_t)((char*)(t2n + (size_t)N * 32) - (char*)d_ws);  // ~50.2 MB

    bool fast = ws_size >= need
             && nbuckets <= MAXB
             && (size_t)nbuckets * CAPMAX <= (size_t)N * NF      // bucket fits in bufA alias
             && (size_t)E * 2 / (size_t)nbuckets <= CAPMAX       // 2x headroom over mean
             && N < (1 << 24)                                    // src fits in 24 bits
             && out_size >= N * 32;

    if (fast) {
        zero_kernel<<<1, 512, 0, stream>>>(gcursor);
        p1_bucket_kernel<<<(E + P1_CHUNK - 1) / P1_CHUNK, 256, 0, stream>>>(
            src, dst, gcursor, bucket, E, nbuckets);
        p2_csr_kernel<<<nbuckets, 256, 0, stream>>>(bucket, gcursor,
                                                    row_start, csr_src, N, nbuckets);
        int dblocks = (N + 127) / 128;
        dense1_mfma_kernel<<<dblocks, 256, 0, stream>>>(x, W_self1, W_neigh1, b1,
                                                        bufA, t1n, N);
        agg64_d2_kernel<<<(N + 15) / 16, 256, 0, stream>>>(
            t1n, bufA, row_start, csr_src, W_self2, W_neigh2, b2, out, t2n, N);
        agg32_kernel<<<(N * 64 + 255) / 256, 256, 0, stream>>>(out, t2n,
                                                               row_start, csr_src, N);
    } else {
        // fallback: atomic path (~51.6 MB)
        float* deg = (float*)d_ws;
        float* agg = deg + N;
        float* h1  = agg + (size_t)N * NF;
        hipMemsetAsync(deg, 0, (size_t)(N + (size_t)N * NF) * sizeof(float), stream);
        deg_kernel<<<(E + 255) / 256, 256, 0, stream>>>(dst, deg, E);
        int at = E * NF;
        agg_atomic_kernel<<<(at + 255) / 256, 256, 0, stream>>>(x, src, dst, agg, E);
        layer1_fb_kernel<<<(N * NF + 255) / 256, 256, 0, stream>>>(x, agg, deg, W_self1,
                                                                   W_neigh1, b1, h1, N);
        hipMemsetAsync(agg, 0, (size_t)N * NF * sizeof(float), stream);
        agg_atomic_kernel<<<(at + 255) / 256, 256, 0, stream>>>(h1, src, dst, agg, E);
        layer2_fb_kernel<<<(N * 32 + 255) / 256, 256, 0, stream>>>(h1, agg, deg, W_self2,
                                                                   W_neigh2, b2, out, N);
    }
}

// Round 12
// 226.464 us; speedup vs baseline: 1.0776x; 1.0776x over previous
//
#include <hip/hip_runtime.h>
#include <hip/hip_bf16.h>

// GraphSAGE 2-layer forward. N=100000, E=1250000, 64 -> 64 -> 32, fp32.
//
// Round-12: round-11 fused structure with the two counter-proven defects fixed:
//  (a) h1s LDS tile padded [16][68] - stride 64 made every MFMA A-read a 16-way
//      bank conflict (8.8M conflict-cycles ~ 14 us);
//  (b) agg gather processes 2 nodes per wave concurrently (half-wave each,
//      4 groups x ILP-2) - 4 serial butterflies/wave dropped concurrency to
//      1.5 TB/s; now 2 serialization points at equal loads-in-flight.
//   zero     : gcursor = 0
//   p1       : bucket edges by dst>>8, pack (src<<8)|rel
//   p2       : per-bucket base (inline prefix) + LDS count/scan -> row_start+csr
//   dense1   : bufA(xs) = x@Ws1+b1 (f32), t1n = bf16(x@Wn1)  (MFMA split-bf16)
//   agg64_d2 : h1 = relu(xs + mean t1n[src]) (LDS tile);
//              d_out = h1@Ws2+b2, t2n = bf16(h1@Wn2)  (MFMA split-bf16)
//   agg32    : d_out += mean t2n[src]   (in place)

#define NF 64
#define BW 256            // bucket width (nodes); rel = dst & 255
#define BSH 8
#define MAXB 512          // max buckets (LDS arrays)
#define CAPMAX 8192       // max edges per bucket region (mean 3197)
#define P1_CHUNK 2048
#define H1S 68            // h1s row stride in floats (68%32=4 -> 2-way banks, free)

typedef __attribute__((ext_vector_type(8))) short short8;
typedef __attribute__((ext_vector_type(8))) unsigned short ushort8v;
typedef __attribute__((ext_vector_type(4))) float floatx4;

__device__ __forceinline__ short bf16hi(float v) {
    __hip_bfloat16 h = __float2bfloat16(v);
    return *(short*)&h;
}
__device__ __forceinline__ float bf2f(short s) {
    __hip_bfloat16 h = *(__hip_bfloat16*)&s;
    return __bfloat162float(h);
}
__device__ __forceinline__ float bits2f(unsigned short u) {
    unsigned int x = ((unsigned int)u) << 16;
    union { unsigned int i; float f; } c; c.i = x; return c.f;
}

// ---------------- zero ----------------

__global__ __launch_bounds__(512) void zero_kernel(int* __restrict__ g) {
    if (threadIdx.x < MAXB) g[threadIdx.x] = 0;
}

// ---------------- CSR build: counting sort ----------------

__global__ __launch_bounds__(256) void p1_bucket_kernel(const int* __restrict__ src,
                                                        const int* __restrict__ dst,
                                                        int* __restrict__ gcursor,
                                                        unsigned* __restrict__ bucket,
                                                        int E, int nbuckets) {
    __shared__ int cnt[MAXB];
    __shared__ int cbase[MAXB];
    const int beg = blockIdx.x * P1_CHUNK;
    const int end = min(E, beg + P1_CHUNK);
    for (int i = threadIdx.x; i < nbuckets; i += 256) cnt[i] = 0;
    __syncthreads();
    for (int e = beg + threadIdx.x; e < end; e += 256)
        atomicAdd(&cnt[dst[e] >> BSH], 1);
    __syncthreads();
    for (int i = threadIdx.x; i < nbuckets; i += 256) {
        int c = cnt[i];
        cbase[i] = c ? atomicAdd(&gcursor[i], c) : 0;
        cnt[i] = 0;                              // reuse as local cursor
    }
    __syncthreads();
    for (int e = beg + threadIdx.x; e < end; e += 256) {
        int d = dst[e];
        int r = d >> BSH;
        int p = cbase[r] + atomicAdd(&cnt[r], 1);
        if (p < CAPMAX)                          // clamp: no OOB even if skewed
            bucket[(size_t)r * CAPMAX + p] = ((unsigned)src[e] << BSH) | (unsigned)(d & (BW - 1));
    }
}

// p2: one block per 256-node bucket; exclusive row_start segment + csr window.
__global__ __launch_bounds__(256) void p2_csr_kernel(const unsigned* __restrict__ bucket,
                                                     const int* __restrict__ gcursor,
                                                     int* __restrict__ row_start,
                                                     int* __restrict__ csr_src,
                                                     int N, int nbuckets) {
    __shared__ unsigned stage[CAPMAX];   // 32 KB
    __shared__ int cnt[BW];
    __shared__ int excl[BW];
    const int r = blockIdx.x;
    const int tid = threadIdx.x;

    // base = sum_{i<r} min(gcursor[i], CAPMAX)   (excl[] as scratch)
    int partial = 0;
    for (int i = tid; i < r; i += 256) partial += min(gcursor[i], CAPMAX);
    excl[tid] = partial;
    __syncthreads();
    for (int off = 128; off > 0; off >>= 1) {
        if (tid < off) excl[tid] += excl[tid + off];
        __syncthreads();
    }
    const int base = excl[0];
    const int sz = min(gcursor[r], CAPMAX);
    const unsigned* bsrc = bucket + (size_t)r * CAPMAX;
    __syncthreads();

    cnt[tid] = 0;
    __syncthreads();
    for (int i = tid; i < sz; i += 256) {
        unsigned v = bsrc[i];
        stage[i] = v;
        atomicAdd(&cnt[v & (BW - 1)], 1);
    }
    __syncthreads();
    // inclusive scan (Hillis-Steele, 1 elem/thread since BW == blockDim)
    excl[tid] = cnt[tid];
    __syncthreads();
    for (int off = 1; off < BW; off <<= 1) {
        int v0 = (tid >= off) ? excl[tid - off] : 0;
        __syncthreads();
        excl[tid] += v0;
        __syncthreads();
    }
    int node = r * BW + tid;
    if (node < N) row_start[node] = base + excl[tid] - cnt[tid];
    if (r == nbuckets - 1 && tid == 0) row_start[N] = base + sz;
    __syncthreads();
    cnt[tid] = excl[tid] - cnt[tid];             // exclusive cursors
    __syncthreads();
    for (int i = tid; i < sz; i += 256) {
        unsigned v = stage[i];
        int p = atomicAdd(&cnt[v & (BW - 1)], 1);
        csr_src[base + p] = (int)(v >> BSH);     // window owned by this block only
    }
}

// ---------------- MFMA dense1: [N][64] @ [64][128] ----------
// A layout: A[m=lane&15][k=(lane>>4)*8+j]; C/D: col=lane&15, row=(lane>>4)*4+reg.
// Weights split+transposed to bf16 hi/lo in LDS. t<4 -> f32 xs+bias; t>=4 -> bf16 t1n.

__global__ __launch_bounds__(256) void dense1_mfma_kernel(
        const float* __restrict__ X,                 // [N][64]
        const float* __restrict__ Wself,             // [64][64] k-major
        const float* __restrict__ Wneigh,            // [64][64] k-major
        const float* __restrict__ bias,              // [64]
        float* __restrict__ outA,                    // [N][64] f32
        unsigned short* __restrict__ outB,           // [N][64] bf16 bits
        int N) {
    constexpr int NT = 8, NSELF = 4, NO = 128, HALF = 64;
    __shared__ unsigned short wh[NO * 72];
    __shared__ unsigned short wl[NO * 72];
    const int tid = threadIdx.x;
    for (int i = tid; i < NO * 64; i += 256) {
        int n = i & (NO - 1), k = i / NO;            // consecutive tid -> coalesced
        float v = (n < HALF) ? Wself[k * HALF + n] : Wneigh[k * HALF + (n - HALF)];
        short hv = bf16hi(v);
        wh[n * 72 + k] = (unsigned short)hv;
        wl[n * 72 + k] = (unsigned short)bf16hi(v - bf2f(hv));
    }

    const int lane = tid & 63;
    const int wid  = tid >> 6;
    const int m = lane & 15, quad = lane >> 4;
    const int rowblk = blockIdx.x * 128 + wid * 32;

    floatx4 acc[2][NT];
    #pragma unroll
    for (int rt = 0; rt < 2; ++rt)
        #pragma unroll
        for (int t = 0; t < NT; ++t) acc[rt][t] = (floatx4)(0.f);

    short8 ah[2][2], al[2][2];   // [rowset][k-half]
    #pragma unroll
    for (int rt = 0; rt < 2; ++rt) {
        int r = rowblk + rt * 16 + m;
        if (r >= N) r = N - 1;                       // clamped load, store guarded
        const float* xp = X + (size_t)r * 64 + quad * 8;
        #pragma unroll
        for (int h = 0; h < 2; ++h) {
            floatx4 f0 = *(const floatx4*)(xp + h * 32);
            floatx4 f1 = *(const floatx4*)(xp + h * 32 + 4);
            short8 hi, lo;
            #pragma unroll
            for (int j = 0; j < 4; ++j) {
                short hv = bf16hi(f0[j]);
                hi[j] = hv; lo[j] = bf16hi(f0[j] - bf2f(hv));
                short hv2 = bf16hi(f1[j]);
                hi[4 + j] = hv2; lo[4 + j] = bf16hi(f1[j] - bf2f(hv2));
            }
            ah[rt][h] = hi; al[rt][h] = lo;
        }
    }
    __syncthreads();                                 // weights staged

    #pragma unroll
    for (int t = 0; t < NT; ++t) {
        int n = t * 16 + m;
        const unsigned short* ph = wh + n * 72 + quad * 8;
        const unsigned short* pl = wl + n * 72 + quad * 8;
        #pragma unroll
        for (int h = 0; h < 2; ++h) {
            short8 bh = *(const short8*)(ph + h * 32);
            short8 bl = *(const short8*)(pl + h * 32);
            #pragma unroll
            for (int rt = 0; rt < 2; ++rt) {
                acc[rt][t] = __builtin_amdgcn_mfma_f32_16x16x32_bf16(ah[rt][h], bh, acc[rt][t], 0, 0, 0);
                acc[rt][t] = __builtin_amdgcn_mfma_f32_16x16x32_bf16(al[rt][h], bh, acc[rt][t], 0, 0, 0);
                acc[rt][t] = __builtin_amdgcn_mfma_f32_16x16x32_bf16(ah[rt][h], bl, acc[rt][t], 0, 0, 0);
            }
        }
    }

    #pragma unroll
    for (int rt = 0; rt < 2; ++rt) {
        #pragma unroll
        for (int t = 0; t < NT; ++t) {
            #pragma unroll
            for (int r4 = 0; r4 < 4; ++r4) {
                int row = rowblk + rt * 16 + quad * 4 + r4;
                if (row < N) {
                    if (t < NSELF) {
                        int col = t * 16 + m;
                        outA[(size_t)row * 64 + col] = acc[rt][t][r4] + bias[col];
                    } else {
                        int col = (t - NSELF) * 16 + m;
                        outB[(size_t)row * 64 + col] = (unsigned short)bf16hi(acc[rt][t][r4]);
                    }
                }
            }
        }
    }
}

// ---------------- fused agg64 + dense2 (MFMA epilogue) ----------------
// Block = 16 nodes, 4 waves. Each wave handles 2 nodes CONCURRENTLY per q-iter
// (half-wave per node, 4 groups x 8 lanes, ILP-2) -> 2 serialization points
// instead of 4. h1 rows -> 16x68 LDS tile (padded; stride 64 was a 16-way
// conflict). Then each wave one 16x16 MFMA tile: cols 0-31 -> d_out(+b2),
// cols 32-63 -> t2n bf16.

__global__ __launch_bounds__(256) void agg64_d2_kernel(
        const unsigned short* __restrict__ t1n,      // [N][64] bf16 bits
        const float* __restrict__ xs,                // [N][64] self+bias
        const int* __restrict__ row_start,
        const int* __restrict__ csr_src,
        const float* __restrict__ Ws2,               // [64][32] k-major
        const float* __restrict__ Wn2,               // [64][32] k-major
        const float* __restrict__ b2,                // [32]
        float* __restrict__ outD,                    // [N][32] (d_out)
        unsigned short* __restrict__ t2n,            // [N][32] bf16 bits
        int N) {
    __shared__ unsigned short w2h[64 * 72];          // 9 KB
    __shared__ unsigned short w2l[64 * 72];          // 9 KB
    __shared__ float h1s[16][H1S];                   // 4.25 KB, padded stride
    const int tid = threadIdx.x;
    for (int i = tid; i < 64 * 64; i += 256) {
        int n = i & 63, k = i >> 6;
        float v = (n < 32) ? Ws2[k * 32 + n] : Wn2[k * 32 + (n - 32)];
        short hv = bf16hi(v);
        w2h[n * 72 + k] = (unsigned short)hv;
        w2l[n * 72 + k] = (unsigned short)bf16hi(v - bf2f(hv));
    }

    const int lane = tid & 63;
    const int wid  = tid >> 6;
    const int half = lane >> 5;                      // node select within pair
    const int g = (lane >> 3) & 3;                   // 4 groups of 8 per node
    const int c = lane & 7;
    const int nbase = blockIdx.x * 16;

    #pragma unroll
    for (int q = 0; q < 2; ++q) {                    // 2 node-pairs per wave
        const int ln = wid * 4 + q * 2 + half;
        const int n = nbase + ln;
        float acc[8] = {0.f, 0.f, 0.f, 0.f, 0.f, 0.f, 0.f, 0.f};
        int beg = 0, end = 0;
        if (n < N) { beg = row_start[n]; end = row_start[n + 1]; }
        for (int j = beg + g; j < end; j += 8) {     // 4 groups, ILP-2
            int j2 = j + 4;
            int s0 = csr_src[j];
            ushort8v u0 = *(const ushort8v*)(t1n + (size_t)s0 * 64 + c * 8);
            if (j2 < end) {
                int s1 = csr_src[j2];
                ushort8v u1 = *(const ushort8v*)(t1n + (size_t)s1 * 64 + c * 8);
                #pragma unroll
                for (int i = 0; i < 8; ++i) acc[i] += bits2f(u0[i]) + bits2f(u1[i]);
            } else {
                #pragma unroll
                for (int i = 0; i < 8; ++i) acc[i] += bits2f(u0[i]);
            }
        }
        #pragma unroll
        for (int i = 0; i < 8; ++i) {                // reduce over 4 groups (in-half)
            float v = acc[i];
            v += __shfl_xor(v, 8);
            v += __shfl_xor(v, 16);
            acc[i] = v;
        }
        if (g == 0) {                                // 8 lanes per half write h1 row
            floatx4 h0, h1v;
            if (n < N) {
                float invd = 1.0f / fmaxf((float)(end - beg), 1.0f);
                size_t o = (size_t)n * 64 + c * 8;
                floatx4 x0 = *(const floatx4*)(xs + o);
                floatx4 x1 = *(const floatx4*)(xs + o + 4);
                #pragma unroll
                for (int i = 0; i < 4; ++i) {
                    h0[i]  = fmaxf(x0[i] + acc[i] * invd, 0.f);
                    h1v[i] = fmaxf(x1[i] + acc[4 + i] * invd, 0.f);
                }
            } else {
                h0 = (floatx4)(0.f); h1v = (floatx4)(0.f);
            }
            *(floatx4*)&h1s[ln][c * 8]     = h0;
            *(floatx4*)&h1s[ln][c * 8 + 4] = h1v;
        }
    }
    __syncthreads();                                 // h1 tile + weights ready

    // dense2: wave wid -> output cols wid*16 .. wid*16+15
    const int m = lane & 15, quad = lane >> 4;
    short8 ah[2], al[2];                             // A = h1s, split hi/lo
    #pragma unroll
    for (int h = 0; h < 2; ++h) {
        const float* hp = &h1s[m][quad * 8 + h * 32];
        floatx4 f0 = *(const floatx4*)hp;
        floatx4 f1 = *(const floatx4*)(hp + 4);
        short8 hi, lo;
        #pragma unroll
        for (int j = 0; j < 4; ++j) {
            short hv = bf16hi(f0[j]);
            hi[j] = hv; lo[j] = bf16hi(f0[j] - bf2f(hv));
            short hv2 = bf16hi(f1[j]);
            hi[4 + j] = hv2; lo[4 + j] = bf16hi(f1[j] - bf2f(hv2));
        }
        ah[h] = hi; al[h] = lo;
    }
    floatx4 acc2 = (floatx4)(0.f);
    const int coln = wid * 16 + m;
    const unsigned short* ph = w2h + coln * 72 + quad * 8;
    const unsigned short* pl = w2l + coln * 72 + quad * 8;
    #pragma unroll
    for (int h = 0; h < 2; ++h) {
        short8 bh = *(const short8*)(ph + h * 32);
        short8 bl = *(const short8*)(pl + h * 32);
        acc2 = __builtin_amdgcn_mfma_f32_16x16x32_bf16(ah[h], bh, acc2, 0, 0, 0);
        acc2 = __builtin_amdgcn_mfma_f32_16x16x32_bf16(al[h], bh, acc2, 0, 0, 0);
        acc2 = __builtin_amdgcn_mfma_f32_16x16x32_bf16(ah[h], bl, acc2, 0, 0, 0);
    }
    #pragma unroll
    for (int r4 = 0; r4 < 4; ++r4) {
        int node = nbase + quad * 4 + r4;
        if (node < N) {
            if (coln < 32) outD[(size_t)node * 32 + coln] = acc2[r4] + b2[coln];
            else t2n[(size_t)node * 32 + (coln - 32)] = (unsigned short)bf16hi(acc2[r4]);
        }
    }
}

// ---------------- agg32: d_out += mean t2n[src], in place ----------------

__global__ __launch_bounds__(256) void agg32_kernel(float* io,  // [N][32] (d_out)
                                                    const unsigned short* __restrict__ t2n,
                                                    const int* __restrict__ row_start,
                                                    const int* __restrict__ csr_src, int N) {
    int n = (blockIdx.x * blockDim.x + threadIdx.x) >> 6;
    if (n >= N) return;
    int lane = threadIdx.x & 63;
    int g = lane >> 2, c = lane & 3;                 // lane covers feats c*8..c*8+7
    int beg = row_start[n], end = row_start[n + 1];
    float acc[8] = {0.f, 0.f, 0.f, 0.f, 0.f, 0.f, 0.f, 0.f};
    for (int j = beg + g; j < end; j += 32) {
        int j2 = j + 16;
        int s0 = csr_src[j];
        ushort8v u0 = *(const ushort8v*)(t2n + (size_t)s0 * 32 + c * 8);
        if (j2 < end) {
            int s1 = csr_src[j2];
            ushort8v u1 = *(const ushort8v*)(t2n + (size_t)s1 * 32 + c * 8);
            #pragma unroll
            for (int i = 0; i < 8; ++i) acc[i] += bits2f(u0[i]) + bits2f(u1[i]);
        } else {
            #pragma unroll
            for (int i = 0; i < 8; ++i) acc[i] += bits2f(u0[i]);
        }
    }
    #pragma unroll
    for (int i = 0; i < 8; ++i) {
        float v = acc[i];
        v += __shfl_xor(v, 4);
        v += __shfl_xor(v, 8);
        v += __shfl_xor(v, 16);
        v += __shfl_xor(v, 32);
        acc[i] = v;
    }
    if (g == 0) {
        float inv = 1.0f / fmaxf((float)(end - beg), 1.0f);
        size_t o = (size_t)n * 32 + c * 8;
        floatx4 s0 = *(const floatx4*)(io + o);
        floatx4 s1 = *(const floatx4*)(io + o + 4);
        floatx4 r0, r1;
        #pragma unroll
        for (int i = 0; i < 4; ++i) {
            r0[i] = s0[i] + acc[i] * inv;
            r1[i] = s1[i] + acc[4 + i] * inv;
        }
        *(floatx4*)(io + o) = r0;
        *(floatx4*)(io + o + 4) = r1;
    }
}

// ---------------- fallback (round-2 atomic path) ----------------

__global__ __launch_bounds__(256) void deg_kernel(const int* __restrict__ dst,
                                                  float* __restrict__ deg, int E) {
    int e = blockIdx.x * blockDim.x + threadIdx.x;
    if (e < E) atomicAdd(&deg[dst[e]], 1.0f);
}

__global__ __launch_bounds__(256) void agg_atomic_kernel(const float* __restrict__ feats,
                                                         const int* __restrict__ src,
                                                         const int* __restrict__ dst,
                                                         float* __restrict__ agg, int E) {
    int tid = blockIdx.x * blockDim.x + threadIdx.x;
    if (tid >= E * NF) return;
    int e = tid >> 6, f = tid & 63;
    atomicAdd(&agg[(size_t)dst[e] * NF + f], feats[(size_t)src[e] * NF + f]);
}

__global__ __launch_bounds__(256) void layer1_fb_kernel(const float* __restrict__ x,
                                                        const float* __restrict__ agg,
                                                        const float* __restrict__ deg,
                                                        const float* __restrict__ Wself,
                                                        const float* __restrict__ Wneigh,
                                                        const float* __restrict__ b,
                                                        float* __restrict__ h1, int N) {
    int tid = blockIdx.x * blockDim.x + threadIdx.x;
    if (tid >= N * NF) return;
    int n = tid >> 6, c = tid & 63;
    float inv = 1.0f / fmaxf(deg[n], 1.0f);
    const float* xrow = x + (size_t)n * NF;
    const float* arow = agg + (size_t)n * NF;
    float acc = b[c];
    #pragma unroll
    for (int k = 0; k < NF; ++k) {
        acc += xrow[k] * Wself[k * NF + c];
        acc += (arow[k] * inv) * Wneigh[k * NF + c];
    }
    h1[tid] = fmaxf(acc, 0.f);
}

__global__ __launch_bounds__(256) void layer2_fb_kernel(const float* __restrict__ h1,
                                                        const float* __restrict__ agg,
                                                        const float* __restrict__ deg,
                                                        const float* __restrict__ Wself,
                                                        const float* __restrict__ Wneigh,
                                                        const float* __restrict__ b,
                                                        float* __restrict__ out, int N) {
    int tid = blockIdx.x * blockDim.x + threadIdx.x;
    if (tid >= N * 32) return;
    int n = tid >> 5, c = tid & 31;
    float inv = 1.0f / fmaxf(deg[n], 1.0f);
    const float* hrow = h1 + (size_t)n * NF;
    const float* arow = agg + (size_t)n * NF;
    float acc = b[c];
    #pragma unroll
    for (int k = 0; k < NF; ++k) {
        acc += hrow[k] * Wself[k * 32 + c];
        acc += (arow[k] * inv) * Wneigh[k * 32 + c];
    }
    out[tid] = acc;
}

// ---------------- launch ----------------

extern "C" void kernel_launch(void* const* d_in, const int* in_sizes, int n_in,
                              void* d_out, int out_size, void* d_ws, size_t ws_size,
                              hipStream_t stream) {
    const float* x        = (const float*)d_in[0];
    const int*   src      = (const int*)d_in[1];
    const int*   dst      = (const int*)d_in[2];
    const float* W_self1  = (const float*)d_in[3];
    const float* W_neigh1 = (const float*)d_in[4];
    const float* b1       = (const float*)d_in[5];
    const float* W_self2  = (const float*)d_in[6];
    const float* W_neigh2 = (const float*)d_in[7];
    const float* b2       = (const float*)d_in[8];
    float* out = (float*)d_out;

    const int N = in_sizes[0] / NF;          // 100000
    const int E = in_sizes[1];               // 1250000
    const int nbuckets = (N + BW - 1) / BW;  // 391

    // ws layout; gather tables 128B-aligned (round-10 proven: unaligned t1n
    // rows straddle 2 cachelines -> +70% FETCH)
    const size_t rsPad = ((size_t)N + 8) & ~7ull;
    int* gcursor   = (int*)d_ws;                      // [MAXB]
    int* row_start = gcursor + MAXB;                  // [N+1] padded
    int* csr_src   = row_start + rsPad;               // [E]
    uintptr_t pa = (uintptr_t)(csr_src + (((size_t)E + 7) & ~7ull));
    pa = (pa + 127) & ~(uintptr_t)127;                // 128B align
    float* bufA = (float*)pa;                         // [N][64] f32 (xs)
    unsigned* bucket = (unsigned*)bufA;               // [nbuckets][CAPMAX], dead before dense1
    unsigned short* t1n = (unsigned short*)(bufA + (size_t)N * NF);  // [N][64] bf16, 128B rows
    unsigned short* t2n = t1n + (size_t)N * NF;                      // [N][32] bf16, 64B rows
    size_t need = (size_t)((char*)(t2n + (size_t)N * 32) - (char*)d_ws);  // ~50.2 MB

    bool fast = ws_size >= need
             && nbuckets <= MAXB
             && (size_t)nbuckets * CAPMAX <= (size_t)N * NF      // bucket fits in bufA alias
             && (size_t)E * 2 / (size_t)nbuckets <= CAPMAX       // 2x headroom over mean
             && N < (1 << 24)                                    // src fits in 24 bits
             && out_size >= N * 32;

    if (fast) {
        zero_kernel<<<1, 512, 0, stream>>>(gcursor);
        p1_bucket_kernel<<<(E + P1_CHUNK - 1) / P1_CHUNK, 256, 0, stream>>>(
            src, dst, gcursor, bucket, E, nbuckets);
        p2_csr_kernel<<<nbuckets, 256, 0, stream>>>(bucket, gcursor,
                                                    row_start, csr_src, N, nbuckets);
        int dblocks = (N + 127) / 128;
        dense1_mfma_kernel<<<dblocks, 256, 0, stream>>>(x, W_self1, W_neigh1, b1,
                                                        bufA, t1n, N);
        agg64_d2_kernel<<<(N + 15) / 16, 256, 0, stream>>>(
            t1n, bufA, row_start, csr_src, W_self2, W_neigh2, b2, out, t2n, N);
        agg32_kernel<<<(N * 64 + 255) / 256, 256, 0, stream>>>(out, t2n,
                                                               row_start, csr_src, N);
    } else {
        // fallback: atomic path (~51.6 MB)
        float* deg = (float*)d_ws;
        float* agg = deg + N;
        float* h1  = agg + (size_t)N * NF;
        hipMemsetAsync(deg, 0, (size_t)(N + (size_t)N * NF) * sizeof(float), stream);
        deg_kernel<<<(E + 255) / 256, 256, 0, stream>>>(dst, deg, E);
        int at = E * NF;
        agg_atomic_kernel<<<(at + 255) / 256, 256, 0, stream>>>(x, src, dst, agg, E);
        layer1_fb_kernel<<<(N * NF + 255) / 256, 256, 0, stream>>>(x, agg, deg, W_self1,
                                                                   W_neigh1, b1, h1, N);
        hipMemsetAsync(agg, 0, (size_t)N * NF * sizeof(float), stream);
        agg_atomic_kernel<<<(at + 255) / 256, 256, 0, stream>>>(h1, src, dst, agg, E);
        layer2_fb_kernel<<<(N * 32 + 255) / 256, 256, 0, stream>>>(h1, agg, deg, W_self2,
                                                                   W_neigh2, b2, out, N);
    }
}

// Round 13
// 214.191 us; speedup vs baseline: 1.1393x; 1.0573x over previous
//
#include <hip/hip_runtime.h>
#include <hip/hip_bf16.h>

// GraphSAGE 2-layer forward. N=100000, E=1250000, 64 -> 64 -> 32, fp32.
//
// Round-13: p1 (edge bucketing) and dense1 (MFMA) are independent -> merged
// into ONE dispatch, blocks partitioned by blockIdx.x (m114: memory-heavy and
// MFMA-heavy waves co-schedule to ~max, not sum). Saves a dispatch gap plus
// ~min(p1,dense1) of serialized time. All else = round-12 (proven 226.5 us).
//   zero      : gcursor = 0
//   p1+dense1 : blocks 0..dblocks-1: bufA(xs)=x@Ws1+b1, t1n=bf16(x@Wn1);
//               blocks dblocks.. : bucket edges by dst>>8, pack (src<<8)|rel
//   p2        : per-bucket base (inline prefix) + LDS count/scan -> row_start+csr
//   agg64_d2  : h1 = relu(xs + mean t1n[src]) (LDS tile, stride 68);
//               d_out = h1@Ws2+b2, t2n = bf16(h1@Wn2)  (MFMA split-bf16)
//   agg32     : d_out += mean t2n[src]   (in place)

#define NF 64
#define BW 256            // bucket width (nodes); rel = dst & 255
#define BSH 8
#define MAXB 512          // max buckets (LDS arrays)
#define CAPMAX 8192       // max edges per bucket region (mean 3197)
#define P1_CHUNK 2048
#define H1S 68            // h1s row stride in floats

typedef __attribute__((ext_vector_type(8))) short short8;
typedef __attribute__((ext_vector_type(8))) unsigned short ushort8v;
typedef __attribute__((ext_vector_type(4))) float floatx4;

__device__ __forceinline__ short bf16hi(float v) {
    __hip_bfloat16 h = __float2bfloat16(v);
    return *(short*)&h;
}
__device__ __forceinline__ float bf2f(short s) {
    __hip_bfloat16 h = *(__hip_bfloat16*)&s;
    return __bfloat162float(h);
}
__device__ __forceinline__ float bits2f(unsigned short u) {
    unsigned int x = ((unsigned int)u) << 16;
    union { unsigned int i; float f; } c; c.i = x; return c.f;
}

// ---------------- zero ----------------

__global__ __launch_bounds__(512) void zero_kernel(int* __restrict__ g) {
    if (threadIdx.x < MAXB) g[threadIdx.x] = 0;
}

// ---------------- fused p1 (bucket) + dense1 (MFMA) ----------------
// Blocks [0, dblocks): dense1. Blocks [dblocks, dblocks+p1blocks): p1.
// Branch is block-uniform; LDS is a union (dense1 36 KB wh/wl vs p1 4 KB).

__global__ __launch_bounds__(256) void p1_dense1_kernel(
        // p1 args
        const int* __restrict__ src, const int* __restrict__ dst,
        int* __restrict__ gcursor, unsigned* __restrict__ bucket,
        int E, int nbuckets, int dblocks,
        // dense1 args
        const float* __restrict__ X,                 // [N][64]
        const float* __restrict__ Wself,             // [64][64] k-major
        const float* __restrict__ Wneigh,            // [64][64] k-major
        const float* __restrict__ bias,              // [64]
        float* __restrict__ outA,                    // [N][64] f32 (xs)
        unsigned short* __restrict__ outB,           // [N][64] bf16 bits (t1n)
        int N) {
    __shared__ int smem_i[9216];                     // 36864 B union
    const int tid = threadIdx.x;

    if ((int)blockIdx.x >= dblocks) {
        // ---------------- p1: bucket the edge list ----------------
        int* cnt   = smem_i;                         // [MAXB]
        int* cbase = smem_i + MAXB;                  // [MAXB]
        const int bid = blockIdx.x - dblocks;
        const int beg = bid * P1_CHUNK;
        const int end = min(E, beg + P1_CHUNK);
        for (int i = tid; i < nbuckets; i += 256) cnt[i] = 0;
        __syncthreads();
        for (int e = beg + tid; e < end; e += 256)
            atomicAdd(&cnt[dst[e] >> BSH], 1);
        __syncthreads();
        for (int i = tid; i < nbuckets; i += 256) {
            int c = cnt[i];
            cbase[i] = c ? atomicAdd(&gcursor[i], c) : 0;
            cnt[i] = 0;                              // reuse as local cursor
        }
        __syncthreads();
        for (int e = beg + tid; e < end; e += 256) {
            int d = dst[e];
            int r = d >> BSH;
            int p = cbase[r] + atomicAdd(&cnt[r], 1);
            if (p < CAPMAX)                          // clamp: no OOB even if skewed
                bucket[(size_t)r * CAPMAX + p] = ((unsigned)src[e] << BSH) | (unsigned)(d & (BW - 1));
        }
        return;
    }

    // ---------------- dense1: [N][64] @ [64][128] MFMA split-bf16 ----------
    // A: A[m=lane&15][k=(lane>>4)*8+j]; C/D: col=lane&15, row=(lane>>4)*4+reg.
    constexpr int NT = 8, NSELF = 4, NO = 128, HALF = 64;
    unsigned short* wh = (unsigned short*)smem_i;            // [NO*72]
    unsigned short* wl = wh + NO * 72;                       // [NO*72]
    for (int i = tid; i < NO * 64; i += 256) {
        int n = i & (NO - 1), k = i / NO;            // consecutive tid -> coalesced
        float v = (n < HALF) ? Wself[k * HALF + n] : Wneigh[k * HALF + (n - HALF)];
        short hv = bf16hi(v);
        wh[n * 72 + k] = (unsigned short)hv;
        wl[n * 72 + k] = (unsigned short)bf16hi(v - bf2f(hv));
    }

    const int lane = tid & 63;
    const int wid  = tid >> 6;
    const int m = lane & 15, quad = lane >> 4;
    const int rowblk = blockIdx.x * 128 + wid * 32;

    floatx4 acc[2][NT];
    #pragma unroll
    for (int rt = 0; rt < 2; ++rt)
        #pragma unroll
        for (int t = 0; t < NT; ++t) acc[rt][t] = (floatx4)(0.f);

    short8 ah[2][2], al[2][2];   // [rowset][k-half]
    #pragma unroll
    for (int rt = 0; rt < 2; ++rt) {
        int r = rowblk + rt * 16 + m;
        if (r >= N) r = N - 1;                       // clamped load, store guarded
        const float* xp = X + (size_t)r * 64 + quad * 8;
        #pragma unroll
        for (int h = 0; h < 2; ++h) {
            floatx4 f0 = *(const floatx4*)(xp + h * 32);
            floatx4 f1 = *(const floatx4*)(xp + h * 32 + 4);
            short8 hi, lo;
            #pragma unroll
            for (int j = 0; j < 4; ++j) {
                short hv = bf16hi(f0[j]);
                hi[j] = hv; lo[j] = bf16hi(f0[j] - bf2f(hv));
                short hv2 = bf16hi(f1[j]);
                hi[4 + j] = hv2; lo[4 + j] = bf16hi(f1[j] - bf2f(hv2));
            }
            ah[rt][h] = hi; al[rt][h] = lo;
        }
    }
    __syncthreads();                                 // weights staged

    #pragma unroll
    for (int t = 0; t < NT; ++t) {
        int n = t * 16 + m;
        const unsigned short* ph = wh + n * 72 + quad * 8;
        const unsigned short* pl = wl + n * 72 + quad * 8;
        #pragma unroll
        for (int h = 0; h < 2; ++h) {
            short8 bh = *(const short8*)(ph + h * 32);
            short8 bl = *(const short8*)(pl + h * 32);
            #pragma unroll
            for (int rt = 0; rt < 2; ++rt) {
                acc[rt][t] = __builtin_amdgcn_mfma_f32_16x16x32_bf16(ah[rt][h], bh, acc[rt][t], 0, 0, 0);
                acc[rt][t] = __builtin_amdgcn_mfma_f32_16x16x32_bf16(al[rt][h], bh, acc[rt][t], 0, 0, 0);
                acc[rt][t] = __builtin_amdgcn_mfma_f32_16x16x32_bf16(ah[rt][h], bl, acc[rt][t], 0, 0, 0);
            }
        }
    }

    #pragma unroll
    for (int rt = 0; rt < 2; ++rt) {
        #pragma unroll
        for (int t = 0; t < NT; ++t) {
            #pragma unroll
            for (int r4 = 0; r4 < 4; ++r4) {
                int row = rowblk + rt * 16 + quad * 4 + r4;
                if (row < N) {
                    if (t < NSELF) {
                        int col = t * 16 + m;
                        outA[(size_t)row * 64 + col] = acc[rt][t][r4] + bias[col];
                    } else {
                        int col = (t - NSELF) * 16 + m;
                        outB[(size_t)row * 64 + col] = (unsigned short)bf16hi(acc[rt][t][r4]);
                    }
                }
            }
        }
    }
}

// ---------------- p2: per-bucket CSR (exclusive window) ----------------

__global__ __launch_bounds__(256) void p2_csr_kernel(const unsigned* __restrict__ bucket,
                                                     const int* __restrict__ gcursor,
                                                     int* __restrict__ row_start,
                                                     int* __restrict__ csr_src,
                                                     int N, int nbuckets) {
    __shared__ unsigned stage[CAPMAX];   // 32 KB
    __shared__ int cnt[BW];
    __shared__ int excl[BW];
    const int r = blockIdx.x;
    const int tid = threadIdx.x;

    // base = sum_{i<r} min(gcursor[i], CAPMAX)   (excl[] as scratch)
    int partial = 0;
    for (int i = tid; i < r; i += 256) partial += min(gcursor[i], CAPMAX);
    excl[tid] = partial;
    __syncthreads();
    for (int off = 128; off > 0; off >>= 1) {
        if (tid < off) excl[tid] += excl[tid + off];
        __syncthreads();
    }
    const int base = excl[0];
    const int sz = min(gcursor[r], CAPMAX);
    const unsigned* bsrc = bucket + (size_t)r * CAPMAX;
    __syncthreads();

    cnt[tid] = 0;
    __syncthreads();
    for (int i = tid; i < sz; i += 256) {
        unsigned v = bsrc[i];
        stage[i] = v;
        atomicAdd(&cnt[v & (BW - 1)], 1);
    }
    __syncthreads();
    // inclusive scan (Hillis-Steele, 1 elem/thread since BW == blockDim)
    excl[tid] = cnt[tid];
    __syncthreads();
    for (int off = 1; off < BW; off <<= 1) {
        int v0 = (tid >= off) ? excl[tid - off] : 0;
        __syncthreads();
        excl[tid] += v0;
        __syncthreads();
    }
    int node = r * BW + tid;
    if (node < N) row_start[node] = base + excl[tid] - cnt[tid];
    if (r == nbuckets - 1 && tid == 0) row_start[N] = base + sz;
    __syncthreads();
    cnt[tid] = excl[tid] - cnt[tid];             // exclusive cursors
    __syncthreads();
    for (int i = tid; i < sz; i += 256) {
        unsigned v = stage[i];
        int p = atomicAdd(&cnt[v & (BW - 1)], 1);
        csr_src[base + p] = (int)(v >> BSH);     // window owned by this block only
    }
}

// ---------------- fused agg64 + dense2 (MFMA epilogue) ----------------
// Block = 16 nodes, 4 waves. Wave handles 2 nodes concurrently per q-iter
// (half-wave per node, 4 groups x 8 lanes, ILP-2). h1 -> 16x68 LDS tile.
// Then each wave one 16x16 MFMA tile: cols 0-31 -> d_out(+b2), 32-63 -> t2n.

__global__ __launch_bounds__(256) void agg64_d2_kernel(
        const unsigned short* __restrict__ t1n,      // [N][64] bf16 bits
        const float* __restrict__ xs,                // [N][64] self+bias
        const int* __restrict__ row_start,
        const int* __restrict__ csr_src,
        const float* __restrict__ Ws2,               // [64][32] k-major
        const float* __restrict__ Wn2,               // [64][32] k-major
        const float* __restrict__ b2,                // [32]
        float* __restrict__ outD,                    // [N][32] (d_out)
        unsigned short* __restrict__ t2n,            // [N][32] bf16 bits
        int N) {
    __shared__ unsigned short w2h[64 * 72];          // 9 KB
    __shared__ unsigned short w2l[64 * 72];          // 9 KB
    __shared__ float h1s[16][H1S];                   // 4.25 KB, padded stride
    const int tid = threadIdx.x;
    for (int i = tid; i < 64 * 64; i += 256) {
        int n = i & 63, k = i >> 6;
        float v = (n < 32) ? Ws2[k * 32 + n] : Wn2[k * 32 + (n - 32)];
        short hv = bf16hi(v);
        w2h[n * 72 + k] = (unsigned short)hv;
        w2l[n * 72 + k] = (unsigned short)bf16hi(v - bf2f(hv));
    }

    const int lane = tid & 63;
    const int wid  = tid >> 6;
    const int half = lane >> 5;                      // node select within pair
    const int g = (lane >> 3) & 3;                   // 4 groups of 8 per node
    const int c = lane & 7;
    const int nbase = blockIdx.x * 16;

    #pragma unroll
    for (int q = 0; q < 2; ++q) {                    // 2 node-pairs per wave
        const int ln = wid * 4 + q * 2 + half;
        const int n = nbase + ln;
        float acc[8] = {0.f, 0.f, 0.f, 0.f, 0.f, 0.f, 0.f, 0.f};
        int beg = 0, end = 0;
        if (n < N) { beg = row_start[n]; end = row_start[n + 1]; }
        for (int j = beg + g; j < end; j += 8) {     // 4 groups, ILP-2
            int j2 = j + 4;
            int s0 = csr_src[j];
            ushort8v u0 = *(const ushort8v*)(t1n + (size_t)s0 * 64 + c * 8);
            if (j2 < end) {
                int s1 = csr_src[j2];
                ushort8v u1 = *(const ushort8v*)(t1n + (size_t)s1 * 64 + c * 8);
                #pragma unroll
                for (int i = 0; i < 8; ++i) acc[i] += bits2f(u0[i]) + bits2f(u1[i]);
            } else {
                #pragma unroll
                for (int i = 0; i < 8; ++i) acc[i] += bits2f(u0[i]);
            }
        }
        #pragma unroll
        for (int i = 0; i < 8; ++i) {                // reduce over 4 groups (in-half)
            float v = acc[i];
            v += __shfl_xor(v, 8);
            v += __shfl_xor(v, 16);
            acc[i] = v;
        }
        if (g == 0) {                                // 8 lanes per half write h1 row
            floatx4 h0, h1v;
            if (n < N) {
                float invd = 1.0f / fmaxf((float)(end - beg), 1.0f);
                size_t o = (size_t)n * 64 + c * 8;
                floatx4 x0 = *(const floatx4*)(xs + o);
                floatx4 x1 = *(const floatx4*)(xs + o + 4);
                #pragma unroll
                for (int i = 0; i < 4; ++i) {
                    h0[i]  = fmaxf(x0[i] + acc[i] * invd, 0.f);
                    h1v[i] = fmaxf(x1[i] + acc[4 + i] * invd, 0.f);
                }
            } else {
                h0 = (floatx4)(0.f); h1v = (floatx4)(0.f);
            }
            *(floatx4*)&h1s[ln][c * 8]     = h0;
            *(floatx4*)&h1s[ln][c * 8 + 4] = h1v;
        }
    }
    __syncthreads();                                 // h1 tile + weights ready

    // dense2: wave wid -> output cols wid*16 .. wid*16+15
    const int m = lane & 15, quad = lane >> 4;
    short8 ah[2], al[2];                             // A = h1s, split hi/lo
    #pragma unroll
    for (int h = 0; h < 2; ++h) {
        const float* hp = &h1s[m][quad * 8 + h * 32];
        floatx4 f0 = *(const floatx4*)hp;
        floatx4 f1 = *(const floatx4*)(hp + 4);
        short8 hi, lo;
        #pragma unroll
        for (int j = 0; j < 4; ++j) {
            short hv = bf16hi(f0[j]);
            hi[j] = hv; lo[j] = bf16hi(f0[j] - bf2f(hv));
            short hv2 = bf16hi(f1[j]);
            hi[4 + j] = hv2; lo[4 + j] = bf16hi(f1[j] - bf2f(hv2));
        }
        ah[h] = hi; al[h] = lo;
    }
    floatx4 acc2 = (floatx4)(0.f);
    const int coln = wid * 16 + m;
    const unsigned short* ph = w2h + coln * 72 + quad * 8;
    const unsigned short* pl = w2l + coln * 72 + quad * 8;
    #pragma unroll
    for (int h = 0; h < 2; ++h) {
        short8 bh = *(const short8*)(ph + h * 32);
        short8 bl = *(const short8*)(pl + h * 32);
        acc2 = __builtin_amdgcn_mfma_f32_16x16x32_bf16(ah[h], bh, acc2, 0, 0, 0);
        acc2 = __builtin_amdgcn_mfma_f32_16x16x32_bf16(al[h], bh, acc2, 0, 0, 0);
        acc2 = __builtin_amdgcn_mfma_f32_16x16x32_bf16(ah[h], bl, acc2, 0, 0, 0);
    }
    #pragma unroll
    for (int r4 = 0; r4 < 4; ++r4) {
        int node = nbase + quad * 4 + r4;
        if (node < N) {
            if (coln < 32) outD[(size_t)node * 32 + coln] = acc2[r4] + b2[coln];
            else t2n[(size_t)node * 32 + (coln - 32)] = (unsigned short)bf16hi(acc2[r4]);
        }
    }
}

// ---------------- agg32: d_out += mean t2n[src], in place ----------------

__global__ __launch_bounds__(256) void agg32_kernel(float* io,  // [N][32] (d_out)
                                                    const unsigned short* __restrict__ t2n,
                                                    const int* __restrict__ row_start,
                                                    const int* __restrict__ csr_src, int N) {
    int n = (blockIdx.x * blockDim.x + threadIdx.x) >> 6;
    if (n >= N) return;
    int lane = threadIdx.x & 63;
    int g = lane >> 2, c = lane & 3;                 // lane covers feats c*8..c*8+7
    int beg = row_start[n], end = row_start[n + 1];
    float acc[8] = {0.f, 0.f, 0.f, 0.f, 0.f, 0.f, 0.f, 0.f};
    for (int j = beg + g; j < end; j += 32) {
        int j2 = j + 16;
        int s0 = csr_src[j];
        ushort8v u0 = *(const ushort8v*)(t2n + (size_t)s0 * 32 + c * 8);
        if (j2 < end) {
            int s1 = csr_src[j2];
            ushort8v u1 = *(const ushort8v*)(t2n + (size_t)s1 * 32 + c * 8);
            #pragma unroll
            for (int i = 0; i < 8; ++i) acc[i] += bits2f(u0[i]) + bits2f(u1[i]);
        } else {
            #pragma unroll
            for (int i = 0; i < 8; ++i) acc[i] += bits2f(u0[i]);
        }
    }
    #pragma unroll
    for (int i = 0; i < 8; ++i) {
        float v = acc[i];
        v += __shfl_xor(v, 4);
        v += __shfl_xor(v, 8);
        v += __shfl_xor(v, 16);
        v += __shfl_xor(v, 32);
        acc[i] = v;
    }
    if (g == 0) {
        float inv = 1.0f / fmaxf((float)(end - beg), 1.0f);
        size_t o = (size_t)n * 32 + c * 8;
        floatx4 s0 = *(const floatx4*)(io + o);
        floatx4 s1 = *(const floatx4*)(io + o + 4);
        floatx4 r0, r1;
        #pragma unroll
        for (int i = 0; i < 4; ++i) {
            r0[i] = s0[i] + acc[i] * inv;
            r1[i] = s1[i] + acc[4 + i] * inv;
        }
        *(floatx4*)(io + o) = r0;
        *(floatx4*)(io + o + 4) = r1;
    }
}

// ---------------- fallback (round-2 atomic path) ----------------

__global__ __launch_bounds__(256) void deg_kernel(const int* __restrict__ dst,
                                                  float* __restrict__ deg, int E) {
    int e = blockIdx.x * blockDim.x + threadIdx.x;
    if (e < E) atomicAdd(&deg[dst[e]], 1.0f);
}

__global__ __launch_bounds__(256) void agg_atomic_kernel(const float* __restrict__ feats,
                                                         const int* __restrict__ src,
                                                         const int* __restrict__ dst,
                                                         float* __restrict__ agg, int E) {
    int tid = blockIdx.x * blockDim.x + threadIdx.x;
    if (tid >= E * NF) return;
    int e = tid >> 6, f = tid & 63;
    atomicAdd(&agg[(size_t)dst[e] * NF + f], feats[(size_t)src[e] * NF + f]);
}

__global__ __launch_bounds__(256) void layer1_fb_kernel(const float* __restrict__ x,
                                                        const float* __restrict__ agg,
                                                        const float* __restrict__ deg,
                                                        const float* __restrict__ Wself,
                                                        const float* __restrict__ Wneigh,
                                                        const float* __restrict__ b,
                                                        float* __restrict__ h1, int N) {
    int tid = blockIdx.x * blockDim.x + threadIdx.x;
    if (tid >= N * NF) return;
    int n = tid >> 6, c = tid & 63;
    float inv = 1.0f / fmaxf(deg[n], 1.0f);
    const float* xrow = x + (size_t)n * NF;
    const float* arow = agg + (size_t)n * NF;
    float acc = b[c];
    #pragma unroll
    for (int k = 0; k < NF; ++k) {
        acc += xrow[k] * Wself[k * NF + c];
        acc += (arow[k] * inv) * Wneigh[k * NF + c];
    }
    h1[tid] = fmaxf(acc, 0.f);
}

__global__ __launch_bounds__(256) void layer2_fb_kernel(const float* __restrict__ h1,
                                                        const float* __restrict__ agg,
                                                        const float* __restrict__ deg,
                                                        const float* __restrict__ Wself,
                                                        const float* __restrict__ Wneigh,
                                                        const float* __restrict__ b,
                                                        float* __restrict__ out, int N) {
    int tid = blockIdx.x * blockDim.x + threadIdx.x;
    if (tid >= N * 32) return;
    int n = tid >> 5, c = tid & 31;
    float inv = 1.0f / fmaxf(deg[n], 1.0f);
    const float* hrow = h1 + (size_t)n * NF;
    const float* arow = agg + (size_t)n * NF;
    float acc = b[c];
    #pragma unroll
    for (int k = 0; k < NF; ++k) {
        acc += hrow[k] * Wself[k * 32 + c];
        acc += (arow[k] * inv) * Wneigh[k * 32 + c];
    }
    out[tid] = acc;
}

// ---------------- launch ----------------

extern "C" void kernel_launch(void* const* d_in, const int* in_sizes, int n_in,
                              void* d_out, int out_size, void* d_ws, size_t ws_size,
                              hipStream_t stream) {
    const float* x        = (const float*)d_in[0];
    const int*   src      = (const int*)d_in[1];
    const int*   dst      = (const int*)d_in[2];
    const float* W_self1  = (const float*)d_in[3];
    const float* W_neigh1 = (const float*)d_in[4];
    const float* b1       = (const float*)d_in[5];
    const float* W_self2  = (const float*)d_in[6];
    const float* W_neigh2 = (const float*)d_in[7];
    const float* b2       = (const float*)d_in[8];
    float* out = (float*)d_out;

    const int N = in_sizes[0] / NF;          // 100000
    const int E = in_sizes[1];               // 1250000
    const int nbuckets = (N + BW - 1) / BW;  // 391

    // ws layout; gather tables 128B-aligned (round-10 proven: unaligned t1n
    // rows straddle 2 cachelines -> +70% FETCH)
    const size_t rsPad = ((size_t)N + 8) & ~7ull;
    int* gcursor   = (int*)d_ws;                      // [MAXB]
    int* row_start = gcursor + MAXB;                  // [N+1] padded
    int* csr_src   = row_start + rsPad;               // [E]
    uintptr_t pa = (uintptr_t)(csr_src + (((size_t)E + 7) & ~7ull));
    pa = (pa + 127) & ~(uintptr_t)127;                // 128B align
    float* bufA = (float*)pa;                         // [N][64] f32 (xs)
    unsigned* bucket = (unsigned*)bufA;               // [nbuckets][CAPMAX], dead before dense1
    unsigned short* t1n = (unsigned short*)(bufA + (size_t)N * NF);  // [N][64] bf16, 128B rows
    unsigned short* t2n = t1n + (size_t)N * NF;                      // [N][32] bf16, 64B rows
    size_t need = (size_t)((char*)(t2n + (size_t)N * 32) - (char*)d_ws);  // ~50.2 MB

    bool fast = ws_size >= need
             && nbuckets <= MAXB
             && (size_t)nbuckets * CAPMAX <= (size_t)N * NF      // bucket fits in bufA alias
             && (size_t)E * 2 / (size_t)nbuckets <= CAPMAX       // 2x headroom over mean
             && N < (1 << 24)                                    // src fits in 24 bits
             && out_size >= N * 32;

    if (fast) {
        zero_kernel<<<1, 512, 0, stream>>>(gcursor);
        int dblocks  = (N + 127) / 128;                          // dense1 blocks
        int p1blocks = (E + P1_CHUNK - 1) / P1_CHUNK;            // p1 blocks
        // NOTE: bucket aliases bufA tail region? No - bucket IS bufA; dense1
        // writes bufA while p1 writes bucket... they alias! Guard: bucket uses
        // [0, nbuckets*CAPMAX) ints = 12.8 MB; bufA is [N][64] f32 = 25.6 MB.
        // Both live in the same launch now -> must NOT alias. Place bucket in
        // t1n+t2n region instead (dead until agg64_d2, written after p2 reads
        // bucket? No - t1n written by dense1 in the SAME launch).
        // => bucket gets its own slot after t2n (ws grew; checked in `need2`).
        unsigned* bucket2 = (unsigned*)(t2n + (((size_t)N * 32 + 63) & ~63ull));
        size_t need2 = (size_t)((char*)(bucket2 + (size_t)nbuckets * CAPMAX) - (char*)d_ws);
        if (ws_size >= need2) {
            p1_dense1_kernel<<<dblocks + p1blocks, 256, 0, stream>>>(
                src, dst, gcursor, bucket2, E, nbuckets, dblocks,
                x, W_self1, W_neigh1, b1, bufA, t1n, N);
            p2_csr_kernel<<<nbuckets, 256, 0, stream>>>(bucket2, gcursor,
                                                        row_start, csr_src, N, nbuckets);
        } else {
            // not enough ws for disjoint bucket: serialize (round-12 order)
            p1_dense1_kernel<<<p1blocks, 256, 0, stream>>>(     // p1 only
                src, dst, gcursor, bucket, E, nbuckets, 0,
                x, W_self1, W_neigh1, b1, bufA, t1n, N);
            p2_csr_kernel<<<nbuckets, 256, 0, stream>>>(bucket, gcursor,
                                                        row_start, csr_src, N, nbuckets);
            p1_dense1_kernel<<<dblocks, 256, 0, stream>>>(      // dense1 only
                src, dst, gcursor, bucket, E, nbuckets, dblocks,
                x, W_self1, W_neigh1, b1, bufA, t1n, N);
        }
        agg64_d2_kernel<<<(N + 15) / 16, 256, 0, stream>>>(
            t1n, bufA, row_start, csr_src, W_self2, W_neigh2, b2, out, t2n, N);
        agg32_kernel<<<(N * 64 + 255) / 256, 256, 0, stream>>>(out, t2n,
                                                               row_start, csr_src, N);
    } else {
        // fallback: atomic path (~51.6 MB)
        float* deg = (float*)d_ws;
        float* agg = deg + N;
        float* h1  = agg + (size_t)N * NF;
        hipMemsetAsync(deg, 0, (size_t)(N + (size_t)N * NF) * sizeof(float), stream);
        deg_kernel<<<(E + 255) / 256, 256, 0, stream>>>(dst, deg, E);
        int at = E * NF;
        agg_atomic_kernel<<<(at + 255) / 256, 256, 0, stream>>>(x, src, dst, agg, E);
        layer1_fb_kernel<<<(N * NF + 255) / 256, 256, 0, stream>>>(x, agg, deg, W_self1,
                                                                   W_neigh1, b1, h1, N);
        hipMemsetAsync(agg, 0, (size_t)N * NF * sizeof(float), stream);
        agg_atomic_kernel<<<(at + 255) / 256, 256, 0, stream>>>(h1, src, dst, agg, E);
        layer2_fb_kernel<<<(N * 32 + 255) / 256, 256, 0, stream>>>(h1, agg, deg, W_self2,
                                                                   W_neigh2, b2, out, N);
    }
}